// Round 3
// baseline (370.102 us; speedup 1.0000x reference)
//
#include <hip/hip_runtime.h>
#include <hip/hip_bf16.h>

typedef unsigned short u16;
typedef __attribute__((ext_vector_type(8))) short bf16x8;
typedef __attribute__((ext_vector_type(8))) unsigned short u16x8;
typedef __attribute__((ext_vector_type(4))) float f32x4;

#define BTOK 4096
#define DDIM 1024
#define NEXP 8
#define HDIM 4096
#define ODIM 1024
#define HC 2048
#define MAXTILES 40
#define MAXROWS (MAXTILES * 128)  // 5120

__device__ __forceinline__ u16 f2bf(float f) {
  unsigned u = __float_as_uint(f);
  return (u16)((u + 0x7FFFu + ((u >> 16) & 1u)) >> 16);  // RNE
}
__device__ __forceinline__ float bf2f(u16 v) {
  return __uint_as_float(((unsigned)v) << 16);
}

__device__ __forceinline__ void gload16(const void* g, void* l) {
  __builtin_amdgcn_global_load_lds(
      (const __attribute__((address_space(1))) void*)g,
      (__attribute__((address_space(3))) void*)l, 16, 0, 0);
}

// ---------------- gating: one wave per token, fp64 accumulate ----------------
__global__ __launch_bounds__(256) void gate_kernel(
    const float* __restrict__ x, const float* __restrict__ Wg,
    const float* __restrict__ bg, int* __restrict__ assign,
    int* __restrict__ counts) {
  int wave = threadIdx.x >> 6;
  int lane = threadIdx.x & 63;
  int b = blockIdx.x * 4 + wave;
  const float* xr = x + (size_t)b * DDIM;
  double acc[NEXP];
#pragma unroll
  for (int e = 0; e < NEXP; ++e) acc[e] = 0.0;
  for (int d = lane; d < DDIM; d += 64) {
    float xv = xr[d];
    const float4* wrow = (const float4*)(Wg + d * NEXP);
    float4 w0 = wrow[0], w1 = wrow[1];
    acc[0] += (double)xv * (double)w0.x;
    acc[1] += (double)xv * (double)w0.y;
    acc[2] += (double)xv * (double)w0.z;
    acc[3] += (double)xv * (double)w0.w;
    acc[4] += (double)xv * (double)w1.x;
    acc[5] += (double)xv * (double)w1.y;
    acc[6] += (double)xv * (double)w1.z;
    acc[7] += (double)xv * (double)w1.w;
  }
#pragma unroll
  for (int e = 0; e < NEXP; ++e) {
    double v = acc[e];
#pragma unroll
    for (int off = 32; off > 0; off >>= 1) v += __shfl_xor(v, off);
    acc[e] = v;
  }
  if (lane == 0) {
    int best = 0;
    double bv = acc[0] + (double)bg[0];
#pragma unroll
    for (int e = 1; e < NEXP; ++e) {
      double v = acc[e] + (double)bg[e];
      if (v > bv) { bv = v; best = e; }  // first max wins (matches jnp.argmax)
    }
    assign[b] = best;
    atomicAdd(&counts[best], 1);
  }
}

// ---------------- setup: offsets, tile table, balance loss ----------------
__global__ void setup_kernel(const int* __restrict__ counts,
                             const float* __restrict__ wbal,
                             int* __restrict__ offp, int* __restrict__ tile_e,
                             int* __restrict__ tile_m, int* __restrict__ meta,
                             float* __restrict__ loss_out) {
  if (threadIdx.x != 0 || blockIdx.x != 0) return;
  int off = 0, nt = 0;
  for (int e = 0; e < NEXP; ++e) {
    offp[e] = off;
    int pc = (counts[e] + 127) & ~127;  // pad to 128
    for (int t = 0; t < (pc >> 7); ++t) {
      tile_e[nt] = e;
      tile_m[nt] = off + t * 128;
      ++nt;
    }
    off += pc;
  }
  offp[NEXP] = off;
  meta[0] = nt;
  float mean = (float)BTOK / (float)NEXP;
  float s = 0.f;
  for (int e = 0; e < NEXP; ++e) {
    float d = (float)counts[e] - mean;
    s += d * d;
  }
  loss_out[0] = s / (float)NEXP * wbal[0];
}

// ---------------- gather: token -> per-expert bucket, fp32 -> bf16 ----------------
__global__ __launch_bounds__(256) void gather_kernel(
    const float* __restrict__ x, const int* __restrict__ assign,
    const int* __restrict__ offp, int* __restrict__ fill,
    int* __restrict__ rowmap, u16* __restrict__ xg) {
  int b = blockIdx.x;
  __shared__ int srow;
  if (threadIdx.x == 0) {
    int e = assign[b];
    int pos = atomicAdd(&fill[e], 1);
    int row = offp[e] + pos;
    rowmap[row] = b;
    srow = row;
  }
  __syncthreads();
  int row = srow;
  float4 v = *(const float4*)(x + (size_t)b * DDIM + threadIdx.x * 4);
  ushort4 o;
  o.x = f2bf(v.x);
  o.y = f2bf(v.y);
  o.z = f2bf(v.z);
  o.w = f2bf(v.w);
  *(ushort4*)(xg + (size_t)row * DDIM + threadIdx.x * 4) = o;
}

// ---------------- transpose+convert: fp32 [K][N] slice -> bf16 [NC][KR] ----------
__global__ __launch_bounds__(256) void transpose_conv(
    const float* __restrict__ W, u16* __restrict__ wt, int inN,
    size_t estrideIn, int k0, int n0, int KR, int NC) {
  const int e = blockIdx.z;
  const int kb = blockIdx.x * 64, nb = blockIdx.y * 64;
  __shared__ float lds[64][68];
  const float* src = W + (size_t)e * estrideIn + (size_t)k0 * inN + n0;
  const int t = threadIdx.x;
  const int rr = t >> 4, cc = (t & 15) * 4;
#pragma unroll
  for (int p = 0; p < 4; ++p) {
    float4 v = *(const float4*)(src + (size_t)(kb + rr + p * 16) * inN + nb + cc);
    *(float4*)&lds[rr + p * 16][cc] = v;
  }
  __syncthreads();
  const int n = t >> 2, kg = (t & 3) * 16;
  u16 tmp[16];
#pragma unroll
  for (int i = 0; i < 16; ++i) tmp[i] = f2bf(lds[kg + i][n]);
  u16* dst = wt + ((size_t)e * NC + nb + n) * KR + kb + kg;
  *(float4*)dst = *(float4*)&tmp[0];
  *(float4*)(dst + 8) = *(float4*)&tmp[8];
}

// ---------------- grouped GEMM: 128x128 tile, K=1024 (32 steps), 2-phase ----
// LDS unit u (16B) holds (r = u>>2, kq = (u&3) ^ ((r>>1)&3)). Fragment b128
// reads then spread 16 lanes over all 8 granule-banks 2-way (free). Staging
// via global_load_lds (linear dest) with inverse-swizzled per-lane source
// (4-lane clusters still cover a contiguous 64B row).
// MODE 0: Hout = relu(acc + bias)  (bf16)
// MODE 1: P[z][row][col] = bf16(acc)
// MODE 2: P[z][row][col] = bf16(bf16(P) + acc)   (unique-writer RMW)
template <int MODE>
__global__ __launch_bounds__(256) void moe_gemm(
    const u16* __restrict__ A, int lda, const u16* __restrict__ BT, int ldb,
    int nbRows, const float* __restrict__ bias, int biasLd, int cOff,
    const int* __restrict__ tile_e, const int* __restrict__ tile_m,
    const int* __restrict__ meta, u16* __restrict__ Hout, int ldh,
    u16* __restrict__ P, size_t pStride) {
  // bijective XCD swizzle within a z-slice (nwg % 8 == 0 for all our grids)
  const int nx = gridDim.x;
  const int nwg = nx * gridDim.y;
  const int orig = blockIdx.y * nx + blockIdx.x;
  const int q = nwg >> 3;
  const int wg = (orig & 7) * q + (orig >> 3);
  const int bx = wg % nx, by = wg / nx;
  if (bx >= meta[0]) return;
  const int e = tile_e[bx];
  const int m0 = tile_m[bx];
  const int n0 = by * 128;
  const int kOff = blockIdx.z << 10;

  __shared__ __align__(16) u16 lds[2 * 8192];  // [buf][A 4096 | B 4096]

  const int tid = threadIdx.x;
  const int lane = tid & 63;
  const int wave = tid >> 6;
  const int wr = wave >> 1, wc = wave & 1;
  const int fr = lane & 15;
  const int kqr = lane >> 4;

  // staging source (inverse swizzle), units tid and tid+256
  const int r0 = tid >> 2, k0 = (tid & 3) ^ ((r0 >> 1) & 3);
  const int r1 = (tid + 256) >> 2, k1 = ((tid + 256) & 3) ^ ((r1 >> 1) & 3);
  const u16* aS0 = A + (size_t)(m0 + r0) * lda + kOff + k0 * 8;
  const u16* aS1 = A + (size_t)(m0 + r1) * lda + kOff + k1 * 8;
  const u16* bPan = BT + ((size_t)e * nbRows + n0) * ldb + kOff;
  const u16* bS0 = bPan + (size_t)r0 * ldb + k0 * 8;
  const u16* bS1 = bPan + (size_t)r1 * ldb + k1 * 8;
  const int dst0 = (tid & ~63) * 8;  // u16 units, lane-linear per wave
  const int dst1 = dst0 + 2048;

  // fragment offsets (u16 units, swizzled)
  int aOff[4], bOff[4];
#pragma unroll
  for (int i = 0; i < 4; ++i) {
    int r = wr * 64 + i * 16 + fr;
    aOff[i] = (r * 4 + (kqr ^ ((r >> 1) & 3))) * 8;
    int c = wc * 64 + i * 16 + fr;
    bOff[i] = (c * 4 + (kqr ^ ((c >> 1) & 3))) * 8;
  }

  f32x4 acc[4][4];
#pragma unroll
  for (int i = 0; i < 4; ++i)
#pragma unroll
    for (int j = 0; j < 4; ++j)
#pragma unroll
      for (int r = 0; r < 4; ++r) acc[i][j][r] = 0.f;

  auto stage = [&](int c, int kt) {
    const int ko = kt * 32;
    u16* base = lds + c * 8192;
    gload16(aS0 + ko, base + dst0);
    gload16(aS1 + ko, base + dst1);
    gload16(bS0 + ko, base + 4096 + dst0);
    gload16(bS1 + ko, base + 4096 + dst1);
  };
  auto compute = [&](int c) {
    const u16* base = lds + c * 8192;
    bf16x8 af[4], bfr[4];
#pragma unroll
    for (int i = 0; i < 4; ++i) {
      af[i] = *(const bf16x8*)(base + aOff[i]);
      bfr[i] = *(const bf16x8*)(base + 4096 + bOff[i]);
    }
#pragma unroll
    for (int i = 0; i < 4; ++i)
#pragma unroll
      for (int j = 0; j < 4; ++j)
        acc[i][j] = __builtin_amdgcn_mfma_f32_16x16x32_bf16(af[i], bfr[j],
                                                            acc[i][j], 0, 0, 0);
  };

  // 2-phase pipeline: one barrier per K-step, stage(t+1) overlaps compute(t)
  stage(0, 0);
  __syncthreads();
  int cur = 0;
#pragma unroll 1
  for (int kt = 0; kt < 31; ++kt) {
    stage(cur ^ 1, kt + 1);
    compute(cur);
    __syncthreads();
    cur ^= 1;
  }
  compute(cur);

  // epilogue: C/D layout col = lane&15, row = (lane>>4)*4 + reg
  if constexpr (MODE == 0) {
#pragma unroll
    for (int i = 0; i < 4; ++i) {
      int rbase = m0 + wr * 64 + i * 16 + (lane >> 4) * 4;
#pragma unroll
      for (int j = 0; j < 4; ++j) {
        int col = n0 + wc * 64 + j * 16 + fr;
        float bv = bias[e * biasLd + cOff + col];
#pragma unroll
        for (int r = 0; r < 4; ++r) {
          float v = acc[i][j][r] + bv;
          v = v > 0.f ? v : 0.f;
          Hout[(size_t)(rbase + r) * ldh + col] = f2bf(v);
        }
      }
    }
  } else {
    u16* Pp = P + blockIdx.z * pStride;
#pragma unroll
    for (int i = 0; i < 4; ++i) {
      int rbase = m0 + wr * 64 + i * 16 + (lane >> 4) * 4;
#pragma unroll
      for (int j = 0; j < 4; ++j) {
        int col = n0 + wc * 64 + j * 16 + fr;
#pragma unroll
        for (int r = 0; r < 4; ++r) {
          size_t idx = (size_t)(rbase + r) * ODIM + col;
          if constexpr (MODE == 1)
            Pp[idx] = f2bf(acc[i][j][r]);
          else
            Pp[idx] = f2bf(bf2f(Pp[idx]) + acc[i][j][r]);
        }
      }
    }
  }
}

// ---------------- reduce: out[tok] = P0 + P1 + b2 ----------------
__global__ __launch_bounds__(256) void reduce_kernel(
    const u16* __restrict__ P, size_t pStride, const int* __restrict__ rowmap,
    const int* __restrict__ tile_e, const int* __restrict__ tile_m,
    const int* __restrict__ meta, const float* __restrict__ b2,
    float* __restrict__ out) {
  if ((int)blockIdx.x >= meta[0]) return;
  const int e = tile_e[blockIdx.x];
  const int row = tile_m[blockIdx.x] + (threadIdx.x >> 1);
  const int tok = rowmap[row];
  if (tok < 0) return;
  const int c0 = blockIdx.y * 128 + (threadIdx.x & 1) * 64;
  const u16* p0 = P + (size_t)row * ODIM;
  const u16* p1 = p0 + pStride;
  float* o = out + (size_t)tok * ODIM;
#pragma unroll
  for (int j = 0; j < 8; ++j) {
    int c = c0 + j * 8;
    u16x8 a = *(const u16x8*)(p0 + c);
    u16x8 b = *(const u16x8*)(p1 + c);
    float4 v0, v1;
    v0.x = bf2f(a[0]) + bf2f(b[0]) + b2[e * ODIM + c + 0];
    v0.y = bf2f(a[1]) + bf2f(b[1]) + b2[e * ODIM + c + 1];
    v0.z = bf2f(a[2]) + bf2f(b[2]) + b2[e * ODIM + c + 2];
    v0.w = bf2f(a[3]) + bf2f(b[3]) + b2[e * ODIM + c + 3];
    v1.x = bf2f(a[4]) + bf2f(b[4]) + b2[e * ODIM + c + 4];
    v1.y = bf2f(a[5]) + bf2f(b[5]) + b2[e * ODIM + c + 5];
    v1.z = bf2f(a[6]) + bf2f(b[6]) + b2[e * ODIM + c + 6];
    v1.w = bf2f(a[7]) + bf2f(b[7]) + b2[e * ODIM + c + 7];
    *(float4*)(o + c) = v0;
    *(float4*)(o + c + 4) = v1;
  }
}

extern "C" void kernel_launch(void* const* d_in, const int* in_sizes, int n_in,
                              void* d_out, int out_size, void* d_ws,
                              size_t ws_size, hipStream_t stream) {
  const float* x = (const float*)d_in[0];
  const float* Wg = (const float*)d_in[1];
  const float* bg = (const float*)d_in[2];
  const float* W1 = (const float*)d_in[3];
  const float* b1 = (const float*)d_in[4];
  const float* W2 = (const float*)d_in[5];
  const float* b2 = (const float*)d_in[6];
  const float* wbal = (const float*)d_in[7];
  float* out = (float*)d_out;

  char* ws = (char*)d_ws;
  int* counts = (int*)(ws + 0);
  int* fill = (int*)(ws + 64);
  int* offp = (int*)(ws + 128);
  int* meta = (int*)(ws + 192);
  int* tile_e = (int*)(ws + 256);
  int* tile_m = (int*)(ws + 512);
  int* assign = (int*)(ws + 4096);
  int* rowmap = (int*)(ws + 20480);
  u16* xg = (u16*)(ws + 65536);                     // 5120 x 1024 bf16 (10.5 MB)
  u16* h = (u16*)(ws + 10551296);                   // 2 x 5120 x 2048 (41.9 MB)
  u16* wt = (u16*)(ws + 52494336);                  // 8 x 2048 x 1024 (33.5 MB)
  u16* P = (u16*)(ws + 86048768);                   // 2 x 5120 x 1024 (21 MB)
  const size_t hChunk = (size_t)MAXROWS * HC;       // u16 elements per h chunk
  const size_t pStride = (size_t)MAXROWS * ODIM;    // u16 elements per partial

  hipMemsetAsync(ws, 0, 4096, stream);
  hipMemsetAsync(rowmap, 0xFF, MAXROWS * 4, stream);
  hipMemsetAsync(xg, 0, (size_t)MAXROWS * DDIM * 2, stream);

  gate_kernel<<<BTOK / 4, 256, 0, stream>>>(x, Wg, bg, assign, counts);
  setup_kernel<<<1, 64, 0, stream>>>(counts, wbal, offp, tile_e, tile_m, meta,
                                     out + (size_t)BTOK * ODIM);
  gather_kernel<<<BTOK, 256, 0, stream>>>(x, assign, offp, fill, rowmap, xg);

  for (int c = 0; c < 2; ++c) {
    u16* hc = h + (size_t)c * hChunk;
    // W1[:, c*HC : (c+1)*HC] -> wt [E][HC][DDIM]
    transpose_conv<<<dim3(DDIM / 64, HC / 64, NEXP), 256, 0, stream>>>(
        W1, wt, HDIM, (size_t)DDIM * HDIM, 0, c * HC, DDIM, HC);
    moe_gemm<0><<<dim3(MAXTILES, HC / 128, 1), 256, 0, stream>>>(
        xg, DDIM, wt, DDIM, HC, b1, HDIM, c * HC, tile_e, tile_m, meta, hc, HC,
        nullptr, 0);
    // W2[c*HC : (c+1)*HC, :] -> wt [E][ODIM][HC]
    transpose_conv<<<dim3(HC / 64, ODIM / 64, NEXP), 256, 0, stream>>>(
        W2, wt, ODIM, (size_t)HDIM * ODIM, c * HC, 0, HC, ODIM);
    if (c == 0)
      moe_gemm<1><<<dim3(MAXTILES, ODIM / 128, 2), 256, 0, stream>>>(
          hc, HC, wt, HC, ODIM, nullptr, 0, 0, tile_e, tile_m, meta, nullptr, 0,
          P, pStride);
    else
      moe_gemm<2><<<dim3(MAXTILES, ODIM / 128, 2), 256, 0, stream>>>(
          hc, HC, wt, HC, ODIM, nullptr, 0, 0, tile_e, tile_m, meta, nullptr, 0,
          P, pStride);
  }
  reduce_kernel<<<dim3(MAXTILES, ODIM / 128), 256, 0, stream>>>(
      P, pStride, rowmap, tile_e, tile_m, meta, b2, out);
}

// Round 4
// 359.947 us; speedup vs baseline: 1.0282x; 1.0282x over previous
//
#include <hip/hip_runtime.h>
#include <hip/hip_bf16.h>

typedef unsigned short u16;
typedef __attribute__((ext_vector_type(8))) short bf16x8;
typedef __attribute__((ext_vector_type(4))) float f32x4;

#define BTOK 4096
#define DDIM 1024
#define NEXP 8
#define HDIM 4096
#define ODIM 1024
#define MAXTILES 40
#define MAXROWS (MAXTILES * 128)  // 5120

__device__ __forceinline__ u16 f2bf(float f) {
  unsigned u = __float_as_uint(f);
  return (u16)((u + 0x7FFFu + ((u >> 16) & 1u)) >> 16);  // RNE
}

__device__ __forceinline__ void gload16(const void* g, void* l) {
  __builtin_amdgcn_global_load_lds(
      (const __attribute__((address_space(1))) void*)g,
      (__attribute__((address_space(3))) void*)l, 16, 0, 0);
}

// ---------------- init: clear control block + rowmap (replaces slow memsets) --
__global__ __launch_bounds__(256) void init_kernel(int* __restrict__ ctrl,
                                                   int* __restrict__ rowmap) {
  int i = blockIdx.x * 256 + threadIdx.x;
  if (i < 1024)
    ctrl[i] = 0;  // counts/fill/offp/meta/tile tables
  else
    rowmap[i - 1024] = -1;  // 5120 entries
}

// ---------------- gating: one wave per token, fp64 accumulate ----------------
__global__ __launch_bounds__(256) void gate_kernel(
    const float* __restrict__ x, const float* __restrict__ Wg,
    const float* __restrict__ bg, int* __restrict__ assign,
    int* __restrict__ counts) {
  int wave = threadIdx.x >> 6;
  int lane = threadIdx.x & 63;
  int b = blockIdx.x * 4 + wave;
  const float* xr = x + (size_t)b * DDIM;
  double acc[NEXP];
#pragma unroll
  for (int e = 0; e < NEXP; ++e) acc[e] = 0.0;
  for (int d = lane; d < DDIM; d += 64) {
    float xv = xr[d];
    const float4* wrow = (const float4*)(Wg + d * NEXP);
    float4 w0 = wrow[0], w1 = wrow[1];
    acc[0] += (double)xv * (double)w0.x;
    acc[1] += (double)xv * (double)w0.y;
    acc[2] += (double)xv * (double)w0.z;
    acc[3] += (double)xv * (double)w0.w;
    acc[4] += (double)xv * (double)w1.x;
    acc[5] += (double)xv * (double)w1.y;
    acc[6] += (double)xv * (double)w1.z;
    acc[7] += (double)xv * (double)w1.w;
  }
#pragma unroll
  for (int e = 0; e < NEXP; ++e) {
    double v = acc[e];
#pragma unroll
    for (int off = 32; off > 0; off >>= 1) v += __shfl_xor(v, off);
    acc[e] = v;
  }
  if (lane == 0) {
    int best = 0;
    double bv = acc[0] + (double)bg[0];
#pragma unroll
    for (int e = 1; e < NEXP; ++e) {
      double v = acc[e] + (double)bg[e];
      if (v > bv) { bv = v; best = e; }  // first max wins (matches jnp.argmax)
    }
    assign[b] = best;
    atomicAdd(&counts[best], 1);
  }
}

// ---------------- setup: offsets, tile table, balance loss ----------------
__global__ void setup_kernel(const int* __restrict__ counts,
                             const float* __restrict__ wbal,
                             int* __restrict__ offp, int* __restrict__ tile_e,
                             int* __restrict__ tile_m, int* __restrict__ meta,
                             float* __restrict__ loss_out) {
  if (threadIdx.x != 0 || blockIdx.x != 0) return;
  int off = 0, nt = 0;
  for (int e = 0; e < NEXP; ++e) {
    offp[e] = off;
    int pc = (counts[e] + 127) & ~127;  // pad to 128
    for (int t = 0; t < (pc >> 7); ++t) {
      tile_e[nt] = e;
      tile_m[nt] = off + t * 128;
      ++nt;
    }
    off += pc;
  }
  offp[NEXP] = off;
  meta[0] = nt;
  float mean = (float)BTOK / (float)NEXP;
  float s = 0.f;
  for (int e = 0; e < NEXP; ++e) {
    float d = (float)counts[e] - mean;
    s += d * d;
  }
  loss_out[0] = s / (float)NEXP * wbal[0];
}

// ---------------- gather: token -> per-expert bucket, fp32 -> bf16 ----------------
__global__ __launch_bounds__(256) void gather_kernel(
    const float* __restrict__ x, const int* __restrict__ assign,
    const int* __restrict__ offp, int* __restrict__ fill,
    int* __restrict__ rowmap, u16* __restrict__ xg) {
  int b = blockIdx.x;
  __shared__ int srow;
  if (threadIdx.x == 0) {
    int e = assign[b];
    int pos = atomicAdd(&fill[e], 1);
    int row = offp[e] + pos;
    rowmap[row] = b;
    srow = row;
  }
  __syncthreads();
  int row = srow;
  float4 v = *(const float4*)(x + (size_t)b * DDIM + threadIdx.x * 4);
  ushort4 o;
  o.x = f2bf(v.x);
  o.y = f2bf(v.y);
  o.z = f2bf(v.z);
  o.w = f2bf(v.w);
  *(ushort4*)(xg + (size_t)row * DDIM + threadIdx.x * 4) = o;
}

// ---------------- transpose+convert: fp32 [K][N] slice -> bf16 [NC][KR] ----------
// Read coalesced along N; LDS pass; write 32B chunks along K.
// LDS read mapping n = t&63 keeps reads at 2-way bank alias (free).
__global__ __launch_bounds__(256) void transpose_conv(
    const float* __restrict__ W, u16* __restrict__ wt, int inN,
    size_t estrideIn, int k0, int n0, int KR, int NC) {
  const int e = blockIdx.z;
  const int kb = blockIdx.x * 64, nb = blockIdx.y * 64;
  __shared__ float lds[64][68];
  const float* src = W + (size_t)e * estrideIn + (size_t)k0 * inN + n0;
  const int t = threadIdx.x;
  const int rr = t >> 4, cc = (t & 15) * 4;
#pragma unroll
  for (int p = 0; p < 4; ++p) {
    float4 v = *(const float4*)(src + (size_t)(kb + rr + p * 16) * inN + nb + cc);
    *(float4*)&lds[rr + p * 16][cc] = v;
  }
  __syncthreads();
  const int n = t & 63, kg = (t >> 6) * 16;
  u16 tmp[16];
#pragma unroll
  for (int i = 0; i < 16; ++i) tmp[i] = f2bf(lds[kg + i][n]);
  u16* dst = wt + ((size_t)e * NC + nb + n) * KR + kb + kg;
  *(float4*)dst = *(float4*)&tmp[0];
  *(float4*)(dst + 8) = *(float4*)&tmp[8];
}

// ---------------- grouped GEMM: 128x128 tile, BK=32, 2-phase dbuf ----------
// LDS unit u (16B) holds (r = u>>2, kq = (u&3) ^ ((r>>1)&3)): linear
// global_load_lds dest + inverse-swizzled per-lane global source; fragment
// b128 reads spread 16 lanes over all 8 granules 2-way (free, m136).
// MODE 0: Hout = relu(acc + bias)   (bf16)
// MODE 1: P[z][row][col] = acc      (fp32 partial)
// MODE 2: P[z][row][col] += acc     (fp32 RMW, later H-chunks; unique writer)
template <int MODE>
__global__ __launch_bounds__(256) void moe_gemm(
    const u16* __restrict__ A, int lda, const u16* __restrict__ BT, int ldb,
    int nbRows, const float* __restrict__ bias, int biasLd, int cOff,
    const int* __restrict__ tile_e, const int* __restrict__ tile_m,
    const int* __restrict__ meta, u16* __restrict__ Hout, int ldh,
    float* __restrict__ P, size_t pStride, int nkt) {
  // bijective XCD swizzle within a z-slice (nwg % 8 == 0 for all our grids)
  const int nx = gridDim.x;
  const int nwg = nx * gridDim.y;
  const int orig = blockIdx.y * nx + blockIdx.x;
  const int q = nwg >> 3;
  const int wg = (orig & 7) * q + (orig >> 3);
  const int bx = wg % nx, by = wg / nx;
  if (bx >= meta[0]) return;
  const int e = tile_e[bx];
  const int m0 = tile_m[bx];
  const int n0 = by * 128;
  const int kOff = blockIdx.z * nkt * 32;

  __shared__ __align__(16) u16 lds[2 * 8192];  // [buf][A 4096 | B 4096]

  const int tid = threadIdx.x;
  const int lane = tid & 63;
  const int wave = tid >> 6;
  const int wr = wave >> 1, wc = wave & 1;
  const int fr = lane & 15;
  const int kqr = lane >> 4;

  // staging source (inverse swizzle), units tid and tid+256
  const int r0 = tid >> 2, k0 = (tid & 3) ^ ((r0 >> 1) & 3);
  const int r1 = (tid + 256) >> 2, k1 = ((tid + 256) & 3) ^ ((r1 >> 1) & 3);
  const u16* aS0 = A + (size_t)(m0 + r0) * lda + kOff + k0 * 8;
  const u16* aS1 = A + (size_t)(m0 + r1) * lda + kOff + k1 * 8;
  const u16* bPan = BT + ((size_t)e * nbRows + n0) * ldb + kOff;
  const u16* bS0 = bPan + (size_t)r0 * ldb + k0 * 8;
  const u16* bS1 = bPan + (size_t)r1 * ldb + k1 * 8;
  const int dst0 = (tid & ~63) * 8;  // u16 units, lane-linear per wave
  const int dst1 = dst0 + 2048;

  // fragment offsets (u16 units, swizzled)
  int aOff[4], bOff[4];
#pragma unroll
  for (int i = 0; i < 4; ++i) {
    int r = wr * 64 + i * 16 + fr;
    aOff[i] = (r * 4 + (kqr ^ ((r >> 1) & 3))) * 8;
    int c = wc * 64 + i * 16 + fr;
    bOff[i] = (c * 4 + (kqr ^ ((c >> 1) & 3))) * 8;
  }

  f32x4 acc[4][4];
#pragma unroll
  for (int i = 0; i < 4; ++i)
#pragma unroll
    for (int j = 0; j < 4; ++j)
#pragma unroll
      for (int r = 0; r < 4; ++r) acc[i][j][r] = 0.f;

  auto stage = [&](int c, int kt) {
    const int ko = kt * 32;
    u16* base = lds + c * 8192;
    gload16(aS0 + ko, base + dst0);
    gload16(aS1 + ko, base + dst1);
    gload16(bS0 + ko, base + 4096 + dst0);
    gload16(bS1 + ko, base + 4096 + dst1);
  };
  auto compute = [&](int c) {
    const u16* base = lds + c * 8192;
    bf16x8 af[4], bfr[4];
#pragma unroll
    for (int i = 0; i < 4; ++i) {
      af[i] = *(const bf16x8*)(base + aOff[i]);
      bfr[i] = *(const bf16x8*)(base + 4096 + bOff[i]);
    }
#pragma unroll
    for (int i = 0; i < 4; ++i)
#pragma unroll
      for (int j = 0; j < 4; ++j)
        acc[i][j] = __builtin_amdgcn_mfma_f32_16x16x32_bf16(af[i], bfr[j],
                                                            acc[i][j], 0, 0, 0);
  };

  // 2-phase pipeline: one barrier per K-step, stage(t+1) overlaps compute(t)
  stage(0, 0);
  __syncthreads();
  int cur = 0;
#pragma unroll 1
  for (int kt = 0; kt < nkt - 1; ++kt) {
    stage(cur ^ 1, kt + 1);
    compute(cur);
    __syncthreads();
    cur ^= 1;
  }
  compute(cur);

  // epilogue: C/D layout col = lane&15, row = (lane>>4)*4 + reg
  if constexpr (MODE == 0) {
#pragma unroll
    for (int i = 0; i < 4; ++i) {
      int rbase = m0 + wr * 64 + i * 16 + (lane >> 4) * 4;
#pragma unroll
      for (int j = 0; j < 4; ++j) {
        int col = n0 + wc * 64 + j * 16 + fr;
        float bv = bias[e * biasLd + cOff + col];
#pragma unroll
        for (int r = 0; r < 4; ++r) {
          float v = acc[i][j][r] + bv;
          v = v > 0.f ? v : 0.f;
          Hout[(size_t)(rbase + r) * ldh + col] = f2bf(v);
        }
      }
    }
  } else {
    float* Pp = P + blockIdx.z * pStride;
#pragma unroll
    for (int i = 0; i < 4; ++i) {
      int rbase = m0 + wr * 64 + i * 16 + (lane >> 4) * 4;
#pragma unroll
      for (int j = 0; j < 4; ++j) {
        int col = n0 + wc * 64 + j * 16 + fr;
#pragma unroll
        for (int r = 0; r < 4; ++r) {
          size_t idx = (size_t)(rbase + r) * ODIM + col;
          if constexpr (MODE == 1)
            Pp[idx] = acc[i][j][r];
          else
            Pp[idx] += acc[i][j][r];
        }
      }
    }
  }
}

// ---------------- reduce: out[tok] = P0 + P1 + b2 ----------------
__global__ __launch_bounds__(256) void reduce_kernel(
    const float* __restrict__ P, size_t pStride, const int* __restrict__ rowmap,
    const int* __restrict__ tile_e, const int* __restrict__ tile_m,
    const int* __restrict__ meta, const float* __restrict__ b2,
    float* __restrict__ out) {
  if ((int)blockIdx.x >= meta[0]) return;
  const int e = tile_e[blockIdx.x];
  const int m0 = tile_m[blockIdx.x];
  const int c0 = blockIdx.y * 128;
#pragma unroll 1
  for (int it = 0; it < 16; ++it) {
    int idx = it * 256 + threadIdx.x;  // 4096 float4 per block
    int r = idx >> 5, cq = idx & 31;   // 32 float4 per 128-col stripe
    int row = m0 + r;
    int tok = rowmap[row];
    if (tok < 0) continue;
    int c = c0 + cq * 4;
    float4 a = *(const float4*)(P + (size_t)row * ODIM + c);
    float4 b = *(const float4*)(P + pStride + (size_t)row * ODIM + c);
    float4 bb = *(const float4*)(b2 + (size_t)e * ODIM + c);
    float4 o;
    o.x = a.x + b.x + bb.x;
    o.y = a.y + b.y + bb.y;
    o.z = a.z + b.z + bb.z;
    o.w = a.w + b.w + bb.w;
    *(float4*)(out + (size_t)tok * ODIM + c) = o;
  }
}

extern "C" void kernel_launch(void* const* d_in, const int* in_sizes, int n_in,
                              void* d_out, int out_size, void* d_ws,
                              size_t ws_size, hipStream_t stream) {
  const float* x = (const float*)d_in[0];
  const float* Wg = (const float*)d_in[1];
  const float* bg = (const float*)d_in[2];
  const float* W1 = (const float*)d_in[3];
  const float* b1 = (const float*)d_in[4];
  const float* W2 = (const float*)d_in[5];
  const float* b2 = (const float*)d_in[6];
  const float* wbal = (const float*)d_in[7];
  float* out = (float*)d_out;

  char* ws = (char*)d_ws;
  int* counts = (int*)(ws + 0);
  int* fill = (int*)(ws + 64);
  int* offp = (int*)(ws + 128);
  int* meta = (int*)(ws + 192);
  int* tile_e = (int*)(ws + 256);
  int* tile_m = (int*)(ws + 512);
  int* assign = (int*)(ws + 4096);
  int* rowmap = (int*)(ws + 20480);
  u16* xg = (u16*)(ws + 65536);  // 5120 x 1024 bf16 = 10.5 MB

  // runtime H-chunk pick: single-shot if ws allows (evidence: ws ~= 512 MiB)
  const size_t hOff = 65536 + (size_t)MAXROWS * DDIM * 2;  // 10,551,296
  auto need = [&](size_t hc) {
    return hOff + (size_t)MAXROWS * hc * 2            // h
           + (size_t)NEXP * hc * DDIM * 2             // wt1
           + (size_t)NEXP * ODIM * hc * 2             // wt2
           + 2 * (size_t)MAXROWS * ODIM * 4;          // P (fp32, z=2)
  };
  size_t HC = 4096;
  if (ws_size < need(4096)) HC = (ws_size >= need(2048)) ? 2048 : 1024;

  u16* h = (u16*)(ws + hOff);
  u16* wt1 = (u16*)((char*)h + (size_t)MAXROWS * HC * 2);
  u16* wt2 = (u16*)((char*)wt1 + (size_t)NEXP * HC * DDIM * 2);
  float* P = (float*)((char*)wt2 + (size_t)NEXP * ODIM * HC * 2);
  const size_t pStride = (size_t)MAXROWS * ODIM;  // floats per partial

  init_kernel<<<24, 256, 0, stream>>>((int*)ws, rowmap);
  gate_kernel<<<BTOK / 4, 256, 0, stream>>>(x, Wg, bg, assign, counts);
  setup_kernel<<<1, 64, 0, stream>>>(counts, wbal, offp, tile_e, tile_m, meta,
                                     out + (size_t)BTOK * ODIM);
  gather_kernel<<<BTOK, 256, 0, stream>>>(x, assign, offp, fill, rowmap, xg);

  const int nch = HDIM / (int)HC;
  for (int c = 0; c < nch; ++c) {
    // W1[:, c*HC:(c+1)*HC] -> wt1 [E][HC][DDIM]
    transpose_conv<<<dim3(DDIM / 64, HC / 64, NEXP), 256, 0, stream>>>(
        W1, wt1, HDIM, (size_t)DDIM * HDIM, 0, c * (int)HC, DDIM, (int)HC);
    moe_gemm<0><<<dim3(MAXTILES, HC / 128, 1), 256, 0, stream>>>(
        xg, DDIM, wt1, DDIM, (int)HC, b1, HDIM, c * (int)HC, tile_e, tile_m,
        meta, h, (int)HC, nullptr, 0, DDIM / 32);
    // W2[c*HC:(c+1)*HC, :] -> wt2 [E][ODIM][HC]
    transpose_conv<<<dim3(HC / 64, ODIM / 64, NEXP), 256, 0, stream>>>(
        W2, wt2, ODIM, (size_t)HDIM * ODIM, c * (int)HC, 0, (int)HC, ODIM);
    if (c == 0)
      moe_gemm<1><<<dim3(MAXTILES, ODIM / 128, 2), 256, 0, stream>>>(
          h, (int)HC, wt2, (int)HC, ODIM, nullptr, 0, 0, tile_e, tile_m, meta,
          nullptr, 0, P, pStride, (int)HC / 64);
    else
      moe_gemm<2><<<dim3(MAXTILES, ODIM / 128, 2), 256, 0, stream>>>(
          h, (int)HC, wt2, (int)HC, ODIM, nullptr, 0, 0, tile_e, tile_m, meta,
          nullptr, 0, P, pStride, (int)HC / 64);
  }
  reduce_kernel<<<dim3(MAXTILES, ODIM / 128), 256, 0, stream>>>(
      P, pStride, rowmap, tile_e, tile_m, meta, b2, out);
}

// Round 5
// 327.812 us; speedup vs baseline: 1.1290x; 1.0980x over previous
//
#include <hip/hip_runtime.h>
#include <hip/hip_bf16.h>

typedef unsigned short u16;
typedef __attribute__((ext_vector_type(8))) short bf16x8;
typedef __attribute__((ext_vector_type(4))) float f32x4;

#define BTOK 4096
#define DDIM 1024
#define NEXP 8
#define HDIM 4096
#define ODIM 1024
#define MAXTILES 40
#define MAXROWS (MAXTILES * 128)  // 5120

__device__ __forceinline__ u16 f2bf(float f) {
  unsigned u = __float_as_uint(f);
  return (u16)((u + 0x7FFFu + ((u >> 16) & 1u)) >> 16);  // RNE
}
__device__ __forceinline__ u16 cvt_bf(float f) {  // HW cvt, RNE
  __hip_bfloat16 h = __float2bfloat16(f);
  u16 r;
  __builtin_memcpy(&r, &h, 2);
  return r;
}

__device__ __forceinline__ void gload16(const void* g, void* l) {
  __builtin_amdgcn_global_load_lds(
      (const __attribute__((address_space(1))) void*)g,
      (__attribute__((address_space(3))) void*)l, 16, 0, 0);
}

// ---------------- init: clear control block + rowmap ----------------
__global__ __launch_bounds__(256) void init_kernel(int* __restrict__ ctrl,
                                                   int* __restrict__ rowmap) {
  int i = blockIdx.x * 256 + threadIdx.x;
  if (i < 1024)
    ctrl[i] = 0;
  else
    rowmap[i - 1024] = -1;  // 5120 entries
}

// ---------------- gating: one wave per token, fp64 accumulate ----------------
__global__ __launch_bounds__(256) void gate_kernel(
    const float* __restrict__ x, const float* __restrict__ Wg,
    const float* __restrict__ bg, int* __restrict__ assign,
    int* __restrict__ counts) {
  int wave = threadIdx.x >> 6;
  int lane = threadIdx.x & 63;
  int b = blockIdx.x * 4 + wave;
  const float* xr = x + (size_t)b * DDIM;
  double acc[NEXP];
#pragma unroll
  for (int e = 0; e < NEXP; ++e) acc[e] = 0.0;
  for (int d = lane; d < DDIM; d += 64) {
    float xv = xr[d];
    const float4* wrow = (const float4*)(Wg + d * NEXP);
    float4 w0 = wrow[0], w1 = wrow[1];
    acc[0] += (double)xv * (double)w0.x;
    acc[1] += (double)xv * (double)w0.y;
    acc[2] += (double)xv * (double)w0.z;
    acc[3] += (double)xv * (double)w0.w;
    acc[4] += (double)xv * (double)w1.x;
    acc[5] += (double)xv * (double)w1.y;
    acc[6] += (double)xv * (double)w1.z;
    acc[7] += (double)xv * (double)w1.w;
  }
#pragma unroll
  for (int e = 0; e < NEXP; ++e) {
    double v = acc[e];
#pragma unroll
    for (int off = 32; off > 0; off >>= 1) v += __shfl_xor(v, off);
    acc[e] = v;
  }
  if (lane == 0) {
    int best = 0;
    double bv = acc[0] + (double)bg[0];
#pragma unroll
    for (int e = 1; e < NEXP; ++e) {
      double v = acc[e] + (double)bg[e];
      if (v > bv) { bv = v; best = e; }  // first max wins (matches jnp.argmax)
    }
    assign[b] = best;
    atomicAdd(&counts[best], 1);
  }
}

// ---------------- setup: offsets, tile table, balance loss ----------------
__global__ void setup_kernel(const int* __restrict__ counts,
                             const float* __restrict__ wbal,
                             int* __restrict__ offp, int* __restrict__ tile_e,
                             int* __restrict__ tile_m, int* __restrict__ meta,
                             float* __restrict__ loss_out) {
  if (threadIdx.x != 0 || blockIdx.x != 0) return;
  int off = 0, nt = 0;
  for (int e = 0; e < NEXP; ++e) {
    offp[e] = off;
    int pc = (counts[e] + 127) & ~127;  // pad to 128
    for (int t = 0; t < (pc >> 7); ++t) {
      tile_e[nt] = e;
      tile_m[nt] = off + t * 128;
      ++nt;
    }
    off += pc;
  }
  offp[NEXP] = off;
  meta[0] = nt;
  float mean = (float)BTOK / (float)NEXP;
  float s = 0.f;
  for (int e = 0; e < NEXP; ++e) {
    float d = (float)counts[e] - mean;
    s += d * d;
  }
  loss_out[0] = s / (float)NEXP * wbal[0];
}

// ---------------- gather: token -> per-expert bucket, fp32 -> bf16 ------------
__global__ __launch_bounds__(256) void gather_kernel(
    const float* __restrict__ x, const int* __restrict__ assign,
    const int* __restrict__ offp, int* __restrict__ fill,
    int* __restrict__ rowmap, u16* __restrict__ xg) {
  int b = blockIdx.x;
  __shared__ int srow;
  if (threadIdx.x == 0) {
    int e = assign[b];
    int pos = atomicAdd(&fill[e], 1);
    int row = offp[e] + pos;
    rowmap[row] = b;
    srow = row;
  }
  __syncthreads();
  int row = srow;
  float4 v = *(const float4*)(x + (size_t)b * DDIM + threadIdx.x * 4);
  ushort4 o;
  o.x = f2bf(v.x);
  o.y = f2bf(v.y);
  o.z = f2bf(v.z);
  o.w = f2bf(v.w);
  *(ushort4*)(xg + (size_t)row * DDIM + threadIdx.x * 4) = o;
}

// ---------------- grouped GEMM with fused B transpose+convert ----------------
// Tile 128x128, BK=32, 4 waves, 2-phase dbuf, one barrier per K-step.
// A (bf16, K-contig): global_load_lds, linear dest, inverse-swizzled source.
// B (fp32 [K][LDN], N-contig): per K-step each thread issues 16 independent
// lane-coalesced strided loads (async split: issued BEFORE compute(t), written
// to LDS after), HW cvt to bf16, 2x ds_write_b128 into the swizzled layout
// unit(r,kq) = r*4 + (kq ^ ((r>>1)&3))  (b128 reads/writes bank-even).
// MODE 0: Hout = relu(acc + bias) bf16;  MODE 1: P[z] = acc (fp32 partials)
template <int MODE, int LDA, int LDN>
__global__ __launch_bounds__(256, 3) void moe_gemm(
    const u16* __restrict__ A, const float* __restrict__ W, size_t eStride,
    const float* __restrict__ bias, const int* __restrict__ tile_e,
    const int* __restrict__ tile_m, const int* __restrict__ meta,
    u16* __restrict__ Hout, float* __restrict__ P, size_t pStride, int nkt) {
  // bijective XCD swizzle (nwg % 8 == 0 for all our grids)
  const int nx = gridDim.x;
  const int nwg = nx * gridDim.y;
  const int orig = blockIdx.y * nx + blockIdx.x;
  const int q = nwg >> 3;
  const int wg = (orig & 7) * q + (orig >> 3);
  const int bx = wg % nx, by = wg / nx;
  if (bx >= meta[0]) return;
  const int e = tile_e[bx];
  const int m0 = tile_m[bx];
  const int n0 = by * 128;
  const int kOff = blockIdx.z * nkt * 32;

  __shared__ __align__(16) u16 lds[2 * 8192];  // [buf][A 4096 | B 4096] u16

  const int tid = threadIdx.x;
  const int lane = tid & 63;
  const int wave = tid >> 6;
  const int wr = wave >> 1, wc = wave & 1;
  const int fr = lane & 15;
  const int kqr = lane >> 4;

  // ---- A staging (global_load_lds, inverse-swizzled source) ----
  const int r0 = tid >> 2, k0 = (tid & 3) ^ ((r0 >> 1) & 3);
  const int r1 = (tid + 256) >> 2, k1 = ((tid + 256) & 3) ^ ((r1 >> 1) & 3);
  const u16* aS0 = A + (size_t)(m0 + r0) * LDA + kOff + k0 * 8;
  const u16* aS1 = A + (size_t)(m0 + r1) * LDA + kOff + k1 * 8;
  const int dst0 = (tid & ~63) * 8;  // u16 units, lane-linear per wave
  const int dst1 = dst0 + 2048;

  // ---- B staging (fused transpose+convert) ----
  const int bc = tid & 127;   // output column 0..127
  const int bq0 = tid >> 7;   // this thread handles k-octs {bq0, bq0+2}
  const float* bRow = W + (size_t)e * eStride + (size_t)kOff * LDN + n0 + bc;
  const int bu0 = (bc * 4 + (bq0 ^ ((bc >> 1) & 3))) * 8;        // u16 units
  const int bu1 = (bc * 4 + ((bq0 + 2) ^ ((bc >> 1) & 3))) * 8;  // u16 units

  // fragment offsets (u16 units, swizzled)
  int aOff[4], bOff[4];
#pragma unroll
  for (int i = 0; i < 4; ++i) {
    int r = wr * 64 + i * 16 + fr;
    aOff[i] = (r * 4 + (kqr ^ ((r >> 1) & 3))) * 8;
    int c = wc * 64 + i * 16 + fr;
    bOff[i] = (c * 4 + (kqr ^ ((c >> 1) & 3))) * 8;
  }

  f32x4 acc[4][4];
#pragma unroll
  for (int i = 0; i < 4; ++i)
#pragma unroll
    for (int j = 0; j < 4; ++j)
#pragma unroll
      for (int r = 0; r < 4; ++r) acc[i][j][r] = 0.f;

  float fb[16];
  auto loadB = [&](int kt) {
    const float* p = bRow + (size_t)kt * 32 * LDN;
#pragma unroll
    for (int i = 0; i < 8; ++i) fb[i] = p[(size_t)(bq0 * 8 + i) * LDN];
#pragma unroll
    for (int i = 0; i < 8; ++i) fb[8 + i] = p[(size_t)((bq0 + 2) * 8 + i) * LDN];
  };
  auto writeB = [&](int c) {
    u16* ldsB = lds + c * 8192 + 4096;
    alignas(16) u16 tA[8], tB[8];
#pragma unroll
    for (int i = 0; i < 8; ++i) tA[i] = cvt_bf(fb[i]);
#pragma unroll
    for (int i = 0; i < 8; ++i) tB[i] = cvt_bf(fb[8 + i]);
    *(bf16x8*)&ldsB[bu0] = *(const bf16x8*)tA;
    *(bf16x8*)&ldsB[bu1] = *(const bf16x8*)tB;
  };
  auto stageA = [&](int c, int kt) {
    const int ko = kt * 32;
    u16* base = lds + c * 8192;
    gload16(aS0 + ko, base + dst0);
    gload16(aS1 + ko, base + dst1);
  };
  auto compute = [&](int c) {
    const u16* base = lds + c * 8192;
    bf16x8 af[4], bfr[4];
#pragma unroll
    for (int i = 0; i < 4; ++i) {
      af[i] = *(const bf16x8*)(base + aOff[i]);
      bfr[i] = *(const bf16x8*)(base + 4096 + bOff[i]);
    }
#pragma unroll
    for (int i = 0; i < 4; ++i)
#pragma unroll
      for (int j = 0; j < 4; ++j)
        acc[i][j] = __builtin_amdgcn_mfma_f32_16x16x32_bf16(af[i], bfr[j],
                                                            acc[i][j], 0, 0, 0);
  };

  // prologue
  loadB(0);
  stageA(0, 0);
  writeB(0);
  __syncthreads();
  int cur = 0;
#pragma unroll 1
  for (int kt = 0; kt < nkt - 1; ++kt) {
    loadB(kt + 1);          // issue B(t+1) loads (latency hidden by compute)
    stageA(cur ^ 1, kt + 1);
    compute(cur);
    writeB(cur ^ 1);        // cvt + LDS write after compute consumed loads
    __syncthreads();
    cur ^= 1;
  }
  compute(cur);

  // epilogue: C/D layout col = lane&15, row = (lane>>4)*4 + reg
  if constexpr (MODE == 0) {
#pragma unroll
    for (int i = 0; i < 4; ++i) {
      int rbase = m0 + wr * 64 + i * 16 + (lane >> 4) * 4;
#pragma unroll
      for (int j = 0; j < 4; ++j) {
        int col = n0 + wc * 64 + j * 16 + fr;
        float bv = bias[e * LDN + col];
#pragma unroll
        for (int r = 0; r < 4; ++r) {
          float v = acc[i][j][r] + bv;
          v = v > 0.f ? v : 0.f;
          Hout[(size_t)(rbase + r) * LDN + col] = f2bf(v);
        }
      }
    }
  } else {
    float* Pp = P + blockIdx.z * pStride;
#pragma unroll
    for (int i = 0; i < 4; ++i) {
      int rbase = m0 + wr * 64 + i * 16 + (lane >> 4) * 4;
#pragma unroll
      for (int j = 0; j < 4; ++j) {
        int col = n0 + wc * 64 + j * 16 + fr;
#pragma unroll
        for (int r = 0; r < 4; ++r)
          Pp[(size_t)(rbase + r) * ODIM + col] = acc[i][j][r];
      }
    }
  }
}

// ---------------- reduce: out[tok] = P0 + P1 + b2 ----------------
__global__ __launch_bounds__(256) void reduce_kernel(
    const float* __restrict__ P, size_t pStride, const int* __restrict__ rowmap,
    const int* __restrict__ tile_e, const int* __restrict__ tile_m,
    const int* __restrict__ meta, const float* __restrict__ b2,
    float* __restrict__ out) {
  if ((int)blockIdx.x >= meta[0]) return;
  const int e = tile_e[blockIdx.x];
  const int m0 = tile_m[blockIdx.x];
  const int c0 = blockIdx.y * 128;
#pragma unroll 1
  for (int it = 0; it < 16; ++it) {
    int idx = it * 256 + threadIdx.x;  // 4096 float4 per block
    int r = idx >> 5, cq = idx & 31;
    int row = m0 + r;
    int tok = rowmap[row];
    if (tok < 0) continue;
    int c = c0 + cq * 4;
    float4 a = *(const float4*)(P + (size_t)row * ODIM + c);
    float4 b = *(const float4*)(P + pStride + (size_t)row * ODIM + c);
    float4 bb = *(const float4*)(b2 + (size_t)e * ODIM + c);
    float4 o;
    o.x = a.x + b.x + bb.x;
    o.y = a.y + b.y + bb.y;
    o.z = a.z + b.z + bb.z;
    o.w = a.w + b.w + bb.w;
    *(float4*)(out + (size_t)tok * ODIM + c) = o;
  }
}

extern "C" void kernel_launch(void* const* d_in, const int* in_sizes, int n_in,
                              void* d_out, int out_size, void* d_ws,
                              size_t ws_size, hipStream_t stream) {
  const float* x = (const float*)d_in[0];
  const float* Wg = (const float*)d_in[1];
  const float* bg = (const float*)d_in[2];
  const float* W1 = (const float*)d_in[3];
  const float* b1 = (const float*)d_in[4];
  const float* W2 = (const float*)d_in[5];
  const float* b2 = (const float*)d_in[6];
  const float* wbal = (const float*)d_in[7];
  float* out = (float*)d_out;

  char* ws = (char*)d_ws;
  int* counts = (int*)(ws + 0);
  int* fill = (int*)(ws + 64);
  int* offp = (int*)(ws + 128);
  int* meta = (int*)(ws + 192);
  int* tile_e = (int*)(ws + 256);
  int* tile_m = (int*)(ws + 512);
  int* assign = (int*)(ws + 4096);
  int* rowmap = (int*)(ws + 20480);
  u16* xg = (u16*)(ws + 65536);                    // 5120 x 1024 bf16 (10.5 MB)
  u16* h = (u16*)(ws + 10551296);                  // 5120 x 4096 bf16 (41.9 MB)
  float* P = (float*)(ws + 52494336);              // 2 x 5120 x 1024 f32 (41.9 MB)
  const size_t pStride = (size_t)MAXROWS * ODIM;   // floats per partial

  init_kernel<<<24, 256, 0, stream>>>((int*)ws, rowmap);
  gate_kernel<<<BTOK / 4, 256, 0, stream>>>(x, Wg, bg, assign, counts);
  setup_kernel<<<1, 64, 0, stream>>>(counts, wbal, offp, tile_e, tile_m, meta,
                                     out + (size_t)BTOK * ODIM);
  gather_kernel<<<BTOK, 256, 0, stream>>>(x, assign, offp, fill, rowmap, xg);

  // GEMM1: h = relu(xg @ W1 + b1)   A: [5120][1024] bf16, B: W1 fp32 [1024][4096]
  moe_gemm<0, DDIM, HDIM><<<dim3(MAXTILES, HDIM / 128, 1), 256, 0, stream>>>(
      xg, W1, (size_t)DDIM * HDIM, b1, tile_e, tile_m, meta, h, nullptr, 0,
      DDIM / 32);
  // GEMM2: P[z] = h @ W2 (K split z=2)   A: [5120][4096] bf16, B: W2 fp32 [4096][1024]
  moe_gemm<1, HDIM, ODIM><<<dim3(MAXTILES, ODIM / 128, 2), 256, 0, stream>>>(
      h, W2, (size_t)HDIM * ODIM, nullptr, tile_e, tile_m, meta, nullptr, P,
      pStride, HDIM / 64);

  reduce_kernel<<<dim3(MAXTILES, ODIM / 128), 256, 0, stream>>>(
      P, pStride, rowmap, tile_e, tile_m, meta, b2, out);
}